// Round 1
// baseline (108.940 us; speedup 1.0000x reference)
//
#include <hip/hip_runtime.h>

#define G 128
#define D_OUT 16

__global__ __launch_bounds__(256) void interp3d_kernel(
    const float* __restrict__ x,
    const float* __restrict__ y,
    const float* __restrict__ xs0,
    const float* __restrict__ xs1,
    const float* __restrict__ xs2,
    float* __restrict__ out,
    int nquery)
{
    __shared__ float sxs[3][G];
    const int tid = threadIdx.x;

    // Stage the three 128-entry grid-coordinate arrays into LDS.
    for (int i = tid; i < 3 * G; i += 256) {
        float v;
        if (i < G)            v = xs0[i];
        else if (i < 2 * G)   v = xs1[i - G];
        else                  v = xs2[i - 2 * G];
        (&sxs[0][0])[i] = v;
    }
    __syncthreads();

    // 4 lanes per query: lane group covers the 16 output channels as 4x float4.
    const int q  = blockIdx.x * 64 + (tid >> 2);
    if (q >= nquery) return;
    const int cg = (tid & 3) * 4;   // channel offset: 0,4,8,12

    int   li[3];
    float t[3];
    #pragma unroll
    for (int d = 0; d < 3; ++d) {
        const float* g = sxs[d];
        float v = x[q * 3 + d];
        // clamped extension
        v = fminf(fmaxf(v, g[0]), g[G - 1]);
        // largest idx with g[idx] <= v (branch-free bitwise binary search, G=128)
        int idx = 0;
        #pragma unroll
        for (int s = 64; s >= 1; s >>= 1) {
            int cand = idx + s;          // max 127
            if (g[cand] <= v) idx = cand;
        }
        if (idx > G - 2) idx = G - 2;    // clip: last cell owns the upper boundary
        float g0 = g[idx], g1 = g[idx + 1];
        li[d] = idx;
        t[d]  = (v - g0) / (g1 - g0);
    }

    const float w0[3] = { 1.f - t[0], 1.f - t[1], 1.f - t[2] };
    const float w1[3] = { t[0], t[1], t[2] };

    float4 acc = make_float4(0.f, 0.f, 0.f, 0.f);
    #pragma unroll
    for (int e = 0; e < 8; ++e) {
        const int e0 = (e >> 2) & 1, e1 = (e >> 1) & 1, e2 = e & 1;
        const float w = (e0 ? w1[0] : w0[0]) * (e1 ? w1[1] : w0[1]) * (e2 ? w1[2] : w0[2]);
        const int idx = ((li[0] + e0) * G + (li[1] + e1)) * G + (li[2] + e2);
        const float4 v = *(const float4*)(y + (size_t)idx * D_OUT + cg);
        acc.x += w * v.x;
        acc.y += w * v.y;
        acc.z += w * v.z;
        acc.w += w * v.w;
    }

    *(float4*)(out + (size_t)q * D_OUT + cg) = acc;
}

extern "C" void kernel_launch(void* const* d_in, const int* in_sizes, int n_in,
                              void* d_out, int out_size, void* d_ws, size_t ws_size,
                              hipStream_t stream) {
    const float* x   = (const float*)d_in[0];
    const float* y   = (const float*)d_in[1];
    const float* xs0 = (const float*)d_in[2];
    const float* xs1 = (const float*)d_in[3];
    const float* xs2 = (const float*)d_in[4];
    float* out = (float*)d_out;

    const int nquery = in_sizes[0] / 3;          // x is (N, 3)
    const int blocks = (nquery + 63) / 64;       // 64 queries per 256-thread block

    hipLaunchKernelGGL(interp3d_kernel, dim3(blocks), dim3(256), 0, stream,
                       x, y, xs0, xs1, xs2, out, nquery);
}